// Round 16
// baseline (167.371 us; speedup 1.0000x reference)
//
#include <hip/hip_runtime.h>

#define N_SRC 50000
#define N_DST 50000
#define N_EDGES 1600000
#define D_NEIGH 128
#define D_SELF 128
#define D_EDGE 32
#define D_OUT 256
#define K_TOT 288
#define D_HN 160

#define NBF 782     // fine buckets of 64 dst nodes
#define CPAD 16     // one counter per 64B line
#define CHUNK 2048
#define CAPSH 12    // 4096-entry padded window (mean 2046, +45 sigma)
#define NSCAT1 256  // scatter blocks inside k_pre

typedef float f32x4 __attribute__((ext_vector_type(4)));
typedef short s16x8 __attribute__((ext_vector_type(8)));
typedef float fv2 __attribute__((ext_vector_type(2)));
typedef unsigned short uv4 __attribute__((ext_vector_type(4)));

__device__ __forceinline__ ushort f2bf(float x) {
    unsigned b = __float_as_uint(x);
    return (ushort)((b + 0x7fffu + ((b >> 16) & 1u)) >> 16);  // RNE
}

// ---------------- OCP e4m3 encode/decode (HW cvt if available) --------------

#if defined(__has_builtin)
#if __has_builtin(__builtin_amdgcn_cvt_pk_fp8_f32) && __has_builtin(__builtin_amdgcn_cvt_pk_f32_fp8)
#define FP8_HW 1
#endif
#endif

__device__ __forceinline__ unsigned enc_fp8_scalar(float x) {  // manual OCP e4m3fn, FTZ
    unsigned b = __float_as_uint(x);
    const unsigned s = b >> 31;
    float ax = fabsf(x);
    ax = fminf(ax, 448.f);
    if (ax < 0.015625f) return s << 7;
    unsigned ab = __float_as_uint(ax);
    unsigned lsb = (ab >> 20) & 1u;
    unsigned b2 = ab + 0x7FFFFu + lsb;
    unsigned e = ((b2 >> 23) & 0xFFu) - 120u;
    unsigned m = (b2 >> 20) & 7u;
    if (e > 15u) { e = 15u; m = 6u; }
    return (s << 7) | (e << 3) | m;
}

__device__ __forceinline__ unsigned enc_fp8x4(float4 f) {
#ifdef FP8_HW
    int r = 0;
    r = __builtin_amdgcn_cvt_pk_fp8_f32(f.x, f.y, r, false);
    r = __builtin_amdgcn_cvt_pk_fp8_f32(f.z, f.w, r, true);
    return (unsigned)r;
#else
    return enc_fp8_scalar(f.x) | (enc_fp8_scalar(f.y) << 8) |
           (enc_fp8_scalar(f.z) << 16) | (enc_fp8_scalar(f.w) << 24);
#endif
}

__device__ __forceinline__ float dec_fp8_scalar(unsigned u) {
    unsigned e = (u >> 3) & 15u;
    unsigned bits = ((u & 0x80u) << 24) | (((u & 0x7Fu) << 20) + (120u << 23));
    return (e == 0) ? 0.f : __uint_as_float(bits);
}

__device__ __forceinline__ void dec_fp8x4(unsigned u, float* f) {
#ifdef FP8_HW
    fv2 lo = __builtin_amdgcn_cvt_pk_f32_fp8(u, false);
    fv2 hi = __builtin_amdgcn_cvt_pk_f32_fp8(u, true);
    f[0] = lo.x; f[1] = lo.y; f[2] = hi.x; f[3] = hi.y;
#else
    f[0] = dec_fp8_scalar(u);
    f[1] = dec_fp8_scalar(u >> 8);
    f[2] = dec_fp8_scalar(u >> 16);
    f[3] = dec_fp8_scalar(u >> 24);
#endif
}

// ---------------- fused pre-pass: radix scatter ∥ hb ∥ hsb ∥ Wb -------------
// blocks [0,256): LDS-staged scatter to 782 padded fine-bucket windows.
// [256,6506): h_neigh->fp8 (hb). [6506,12756): h_self->bf16 (hsb).
// [12756,12792): W->bf16 fragment layout Wb[t][koff8][c][8].
// pk1 entry: x = edge id; y = src(16b) | dl(6b)<<16 | cb(10b)<<22.

__global__ __launch_bounds__(256) void k_pre(const int* __restrict__ dst,
                                             const int* __restrict__ src,
                                             int* __restrict__ gcur0,
                                             int2* __restrict__ pk1,
                                             const float* __restrict__ h_neigh,
                                             unsigned* __restrict__ hb,
                                             const float* __restrict__ h_self,
                                             ushort* __restrict__ hsb,
                                             const float* __restrict__ Wself,
                                             const float* __restrict__ Wneigh,
                                             ushort* __restrict__ Wb) {
    __shared__ int hist[NBF];
    __shared__ int lbase[NBF];
    __shared__ int gbase[NBF];
    __shared__ int partial[256];
    __shared__ int2 stage[CHUNK];
    const int blk = blockIdx.x;
    const int tid = threadIdx.x;

    if (blk >= NSCAT1) {
        const int bb = blk - NSCAT1;
        if (bb < 6250) {                       // hb: f32x4 -> fp8x4
            const int i = bb * 256 + tid;
            float4 f = ((const float4*)h_neigh)[i];
            hb[i] = enc_fp8x4(f);
        } else if (bb < 12500) {               // hsb: f32x4 -> bf16x4
            const int i = (bb - 6250) * 256 + tid;
            float4 f = ((const float4*)h_self)[i];
            ((ushort4*)hsb)[i] = make_ushort4(f2bf(f.x), f2bf(f.y), f2bf(f.z), f2bf(f.w));
        } else {                               // Wb
            const int q = (bb - 12500) * 256 + tid;
            if (q >= 9 * 4 * 256) return;
            const int t = q >> 10;
            const int r = q & 1023;
            const int k8 = r >> 8;
            const int c = r & 255;
            const int kb = t * 32 + k8 * 8;
            const float* p = (kb < 128) ? (Wself + (size_t)c * D_SELF + kb)
                                        : (Wneigh + (size_t)c * D_HN + (kb - 128));
            float4 f0 = *(const float4*)(p);
            float4 f1 = *(const float4*)(p + 4);
            ushort* o = Wb + (size_t)q * 8;
            *(ushort4*)(o)     = make_ushort4(f2bf(f0.x), f2bf(f0.y), f2bf(f0.z), f2bf(f0.w));
            *(ushort4*)(o + 4) = make_ushort4(f2bf(f1.x), f2bf(f1.y), f2bf(f1.z), f2bf(f1.w));
        }
        return;
    }

    // ---- scatter (blocks 0..255) ----
    const int n = N_EDGES;
    for (int c0 = blk * CHUNK; c0 < n; c0 += NSCAT1 * CHUNK) {
        const int m = min(CHUNK, n - c0);
        for (int t = tid; t < NBF; t += 256) hist[t] = 0;
        __syncthreads();
        int d8[8], s8[8];
#pragma unroll
        for (int j = 0; j < 8; j++) {
            const int i = c0 + j * 256 + tid;
            if (i < n) { d8[j] = dst[i]; s8[j] = src[i]; atomicAdd(&hist[d8[j] >> 6], 1); }
        }
        __syncthreads();
        // parallel exclusive scan over NBF bins: 4 bins/thread + 256-wide scan
        int loc[4];
        int sum = 0;
#pragma unroll
        for (int j = 0; j < 4; j++) {
            const int bi = tid * 4 + j;
            loc[j] = (bi < NBF) ? hist[bi] : 0;
            sum += loc[j];
        }
        partial[tid] = sum;
        __syncthreads();
        for (int off = 1; off < 256; off <<= 1) {
            int q = (tid >= off) ? partial[tid - off] : 0;
            __syncthreads();
            partial[tid] += q;
            __syncthreads();
        }
        int ex = (tid == 0) ? 0 : partial[tid - 1];
#pragma unroll
        for (int j = 0; j < 4; j++) {
            const int bi = tid * 4 + j;
            if (bi < NBF) { lbase[bi] = ex; ex += loc[j]; }
        }
        __syncthreads();
        for (int t = tid; t < NBF; t += 256)
            gbase[t] = hist[t] ? atomicAdd(&gcur0[t * CPAD], hist[t]) : 0;
        __syncthreads();
        for (int t = tid; t < NBF; t += 256) hist[t] = lbase[t];
        __syncthreads();
#pragma unroll
        for (int j = 0; j < 8; j++) {
            const int i = c0 + j * 256 + tid;
            if (i < n) {
                const unsigned cb = (unsigned)d8[j] >> 6;
                const int p = atomicAdd(&hist[cb], 1);
                stage[p] = make_int2(i, (int)((unsigned)s8[j] |
                                              (((unsigned)d8[j] & 63u) << 16) | (cb << 22)));
            }
        }
        __syncthreads();
        for (int t = tid; t < m; t += 256) {
            int2 v2 = stage[t];
            const unsigned cb = ((unsigned)v2.y >> 22) & 1023u;
            v2.y &= 0x3FFFFF;
            pk1[((size_t)cb << CAPSH) + gbase[cb] + (t - lbase[cb])] = v2;
        }
        __syncthreads();
    }
}

// ---------------- pass B: per-fine-bucket sort -> per-dst runs + rs2 --------
// 782 blocks x 256 threads; 64 bins; single-wave shfl-scan.

__global__ __launch_bounds__(256) void k_scat2(const int* __restrict__ gcur0,
                                               const int2* __restrict__ pk1,
                                               int2* __restrict__ pk2,
                                               int2* __restrict__ rs2) {
    __shared__ int h[64];
    __shared__ int cur[64];
    const int b = blockIdx.x;
    const int n = min(gcur0[b * CPAD], 1 << CAPSH);
    const int base = b << CAPSH;
    const int tid = threadIdx.x;
    if (tid < 64) h[tid] = 0;
    __syncthreads();

    int2 ent[16];
    int ne = 0;
    for (int i = tid; i < n; i += 256) {
        ent[ne] = pk1[base + i];
        atomicAdd(&h[(ent[ne].y >> 16) & 63], 1);
        ne++;
    }
    __syncthreads();
    if (tid < 64) {          // wave 0: inclusive shfl-scan over 64 bins
        const int v = h[tid];
        int p = v;
#pragma unroll
        for (int off = 1; off < 64; off <<= 1) {
            int q = __shfl_up(p, off);
            if (tid >= off) p += q;
        }
        cur[tid] = p - v;
        const int gn = b * 64 + tid;
        if (gn < N_DST) rs2[gn] = make_int2(base + p - v, base + p);
    }
    __syncthreads();
    for (int j = 0; j < ne; j++) {
        const int dl = (ent[j].y >> 16) & 63;
        const int p = atomicAdd(&cur[dl], 1);
        pk2[base + p] = make_int2(ent[j].x, ent[j].y & 0xFFFF);
    }
}

// ---------------- Aggregation: one wave per dst, 2 dsts per block -----------
// Half-wave split gathers; hb rows fp8 e4m3 (128B/row, 4B/lane).
// Zero-reuse streams (pk, ef) NON-TEMPORAL; hb stays cache-resident.

__global__ __launch_bounds__(128) void k_agg(const int2* __restrict__ rs2,
                                             const int2* __restrict__ pk,
                                             const unsigned char* __restrict__ hb,
                                             const float* __restrict__ ef,
                                             ushort* __restrict__ hnb) {
    const int d = blockIdx.x * 2 + (threadIdx.x >> 6);
    const int lane = threadIdx.x & 63;
    if (d >= N_DST) return;
    const int ll = lane & 31;
    const int g = lane >> 5;
    const int2 se = rs2[d];
    const int start = se.x, end = se.y;
    const int deg = end - start;
    float a0 = 0.f, a1 = 0.f, a2 = 0.f, a3 = 0.f, ae = 0.f;
    const unsigned char* hbase = hb + 4 * ll;
    const float* ebase = ef + ll;

    for (int c = start; c < end; c += 64) {
        const int rem = end - c;
        const int m = rem < 64 ? rem : 64;
        int e = 0, s = 0;
        if (lane < m) {
            unsigned long long pv =
                __builtin_nontemporal_load((const unsigned long long*)&pk[c + lane]);
            e = (int)(unsigned)pv;
            s = (int)(unsigned)(pv >> 32);
        }
        int i = 0;
        for (; i + 16 <= m; i += 16) {
            unsigned u[8];
            float te[8];
#pragma unroll
            for (int j = 0; j < 8; j++) {
                const int sj = __shfl(s, i + 2 * j + g);
                u[j] = *(const unsigned*)(hbase + (size_t)sj * D_NEIGH);
            }
#pragma unroll
            for (int j = 0; j < 8; j++) {
                const int ee = __shfl(e, i + 2 * j + g);
                te[j] = __builtin_nontemporal_load(ebase + (size_t)ee * D_EDGE);
            }
#pragma unroll
            for (int j = 0; j < 8; j++) {
                float f[4];
                dec_fp8x4(u[j], f);
                a0 += f[0]; a1 += f[1]; a2 += f[2]; a3 += f[3];
                ae += te[j];
            }
        }
        for (; i + 8 <= m; i += 8) {
            unsigned u[4];
            float te[4];
#pragma unroll
            for (int j = 0; j < 4; j++) {
                const int sj = __shfl(s, i + 2 * j + g);
                u[j] = *(const unsigned*)(hbase + (size_t)sj * D_NEIGH);
            }
#pragma unroll
            for (int j = 0; j < 4; j++) {
                const int ee = __shfl(e, i + 2 * j + g);
                te[j] = __builtin_nontemporal_load(ebase + (size_t)ee * D_EDGE);
            }
#pragma unroll
            for (int j = 0; j < 4; j++) {
                float f[4];
                dec_fp8x4(u[j], f);
                a0 += f[0]; a1 += f[1]; a2 += f[2]; a3 += f[3];
                ae += te[j];
            }
        }
        for (; i < m; ++i) {   // tail singles: half-wave 0 only
            const int si = __builtin_amdgcn_readlane(s, i);
            const int ei = __builtin_amdgcn_readlane(e, i);
            if (g == 0) {
                const unsigned uu = *(const unsigned*)(hbase + (size_t)si * D_NEIGH);
                float f[4];
                dec_fp8x4(uu, f);
                a0 += f[0]; a1 += f[1]; a2 += f[2]; a3 += f[3];
                ae += __builtin_nontemporal_load(ebase + (size_t)ei * D_EDGE);
            }
        }
    }

    a0 += __shfl_xor(a0, 32); a1 += __shfl_xor(a1, 32);
    a2 += __shfl_xor(a2, 32); a3 += __shfl_xor(a3, 32);
    ae += __shfl_xor(ae, 32);

    if (lane < 32) {
        const float inv = 1.0f / (float)(deg > 0 ? deg : 1);
        ushort* o = hnb + (size_t)d * D_HN;
        *(ushort4*)(o + 4 * ll) = make_ushort4(f2bf(a0 * inv), f2bf(a1 * inv),
                                               f2bf(a2 * inv), f2bf(a3 * inv));
        o[128 + ll] = f2bf(ae * inv);
    }
}

// ---------------- Fused bf16-MFMA GEMM + ReLU + row-L2-norm ----------------
// 128x256, 512 threads (8 waves 4x2). X (hsb|hnb bf16): LDS double-buffered,
// one barrier per K-step. W: B-fragments from L2-resident Wb.

#define GBM 128

__global__ __launch_bounds__(512) void k_gemm_norm(const ushort* __restrict__ hsb,
                                                   const ushort* __restrict__ hnb,
                                                   const ushort* __restrict__ Wb,
                                                   float* __restrict__ out) {
    __shared__ __align__(16) ushort Xs[2][GBM * 40];
    __shared__ float rsum[2][GBM];
    __shared__ float invn[GBM];

    const int tid = threadIdx.x;
    const int lane = tid & 63;
    const int wid = tid >> 6;
    const int wm = wid >> 1;
    const int wn = wid & 1;
    const int brow = blockIdx.x * GBM;
    const int xrow = tid >> 2, xpart = tid & 3;
    const int koff8 = lane >> 4, rsel = lane & 15;

    f32x4 acc[2][8] = {};

    auto stageX = [&](int t, int bufi) {
        const int k0 = t * 32;
        const int gr = brow + xrow;
        uv4 v0 = (uv4)0, v1 = (uv4)0;
        if (gr < N_DST) {
            const ushort* sp = (k0 < 128) ? (hsb + (size_t)gr * D_SELF + k0 + xpart * 8)
                                          : (hnb + (size_t)gr * D_HN + (k0 - 128) + xpart * 8);
            v0 = __builtin_nontemporal_load((const uv4*)(sp));
            v1 = __builtin_nontemporal_load((const uv4*)(sp + 4));
        }
        *(uv4*)&Xs[bufi][xrow * 40 + xpart * 8] = v0;
        *(uv4*)&Xs[bufi][xrow * 40 + xpart * 8 + 4] = v1;
    };

    stageX(0, 0);
    __syncthreads();

    for (int t = 0; t < 9; t++) {
        if (t < 8) stageX(t + 1, (t + 1) & 1);
        s16x8 af[2], bf[8];
#pragma unroll
        for (int fi = 0; fi < 2; fi++)
            af[fi] = *(const s16x8*)&Xs[t & 1][(wm * 32 + fi * 16 + rsel) * 40 + koff8 * 8];
#pragma unroll
        for (int fj = 0; fj < 8; fj++)
            bf[fj] = *(const s16x8*)&Wb[((size_t)(t * 4 + koff8) * 256 +
                                         (wn * 128 + fj * 16 + rsel)) * 8];
#pragma unroll
        for (int fi = 0; fi < 2; fi++)
#pragma unroll
            for (int fj = 0; fj < 8; fj++)
                acc[fi][fj] = __builtin_amdgcn_mfma_f32_16x16x32_bf16(af[fi], bf[fj], acc[fi][fj], 0, 0, 0);
        __syncthreads();
    }

    float ss[2][4];
#pragma unroll
    for (int fi = 0; fi < 2; fi++)
#pragma unroll
        for (int j = 0; j < 4; j++) {
            float s = 0.f;
#pragma unroll
            for (int fj = 0; fj < 8; fj++) {
                float z = fmaxf(acc[fi][fj][j], 0.f);
                acc[fi][fj][j] = z;
                s += z * z;
            }
            ss[fi][j] = s;
        }
#pragma unroll
    for (int m = 1; m < 16; m <<= 1)
#pragma unroll
        for (int fi = 0; fi < 2; fi++)
#pragma unroll
            for (int j = 0; j < 4; j++) ss[fi][j] += __shfl_xor(ss[fi][j], m);
    if ((lane & 15) == 0) {
        const int gg = lane >> 4;
#pragma unroll
        for (int fi = 0; fi < 2; fi++)
#pragma unroll
            for (int j = 0; j < 4; j++)
                rsum[wn][wm * 32 + fi * 16 + gg * 4 + j] = ss[fi][j];
    }
    __syncthreads();
    if (tid < GBM) {
        float t = rsum[0][tid] + rsum[1][tid];
        invn[tid] = (t > 0.f) ? 1.f / sqrtf(t) : 1.f;
    }
    __syncthreads();

#pragma unroll
    for (int fi = 0; fi < 2; fi++)
#pragma unroll
        for (int j = 0; j < 4; j++) {
            const int rl = wm * 32 + fi * 16 + (lane >> 4) * 4 + j;
            const int row = brow + rl;
            if (row < N_DST) {
                const float iv = invn[rl];
#pragma unroll
                for (int fj = 0; fj < 8; fj++)
                    __builtin_nontemporal_store(acc[fi][fj][j] * iv,
                        &out[(size_t)row * D_OUT + wn * 128 + fj * 16 + (lane & 15)]);
            }
        }
}

// ---------------- launch ----------------

extern "C" void kernel_launch(void* const* d_in, const int* in_sizes, int n_in,
                              void* d_out, int out_size, void* d_ws, size_t ws_size,
                              hipStream_t stream) {
    const float* h_neigh = (const float*)d_in[0];
    const float* h_self  = (const float*)d_in[1];
    const float* ef      = (const float*)d_in[2];
    const int*   src     = (const int*)d_in[3];
    const int*   dst     = (const int*)d_in[4];
    const float* Wself   = (const float*)d_in[5];
    const float* Wneigh  = (const float*)d_in[6];
    float* out = (float*)d_out;

    char* ws = (char*)d_ws;
    // layout (NBF<<CAPSH = 3,203,072 entries per pk array = 25.6MB)
    int*      gcur0 = (int*)(ws + 0);                          // 50KB, reserve 64KB
    int2*     rs2   = (int2*)(ws + 65536);                     // 400KB, reserve to 524288
    int2*     pk1   = (int2*)(ws + 524288);                    // 25.6MB -> 26,148,864
    int2*     pk2   = (int2*)(ws + 26148864);                  // 25.6MB -> 51,773,440
    unsigned* hb    = (unsigned*)(ws + 51773440);              // 6.4MB  -> 58,173,440
    ushort*   hsb   = (ushort*)(ws + 58173440);                // 12.8MB -> 70,973,440
    ushort*   hnb   = (ushort*)(ws + 70973440);                // 16MB   -> 86,973,440
    ushort*   Wb    = (ushort*)(ws + 86973440);                // 147KB  -> 87,120,896

    hipMemsetAsync(gcur0, 0, NBF * CPAD * sizeof(int), stream);
    k_pre<<<NSCAT1 + 6250 + 6250 + 36, 256, 0, stream>>>(dst, src, gcur0, pk1,
                                                         h_neigh, hb, h_self, hsb,
                                                         Wself, Wneigh, Wb);
    k_scat2<<<NBF, 256, 0, stream>>>(gcur0, pk1, pk2, rs2);
    k_agg<<<(N_DST + 1) / 2, 128, 0, stream>>>(rs2, pk2, (const unsigned char*)hb, ef, hnb);
    k_gemm_norm<<<(N_DST + GBM - 1) / GBM, 512, 0, stream>>>(hsb, hnb, Wb, out);
}

// Round 17
// 152.149 us; speedup vs baseline: 1.1000x; 1.1000x over previous
//
#include <hip/hip_runtime.h>

#define N_SRC 50000
#define N_DST 50000
#define N_EDGES 1600000
#define D_NEIGH 128
#define D_SELF 128
#define D_EDGE 32
#define D_OUT 256
#define K_TOT 288
#define D_HN 160

#define NB 196      // coarse buckets of 256 dst nodes (CHUNK/NB ~10 entries: full-line bursts)
#define CPAD 16     // one counter per 64B line
#define CHUNK 2048
#define CAPSH 14    // 16384-entry padded window per bucket (mean 8163, +90 sigma)
#define NSCAT1 256  // scatter blocks inside k_pre

typedef float f32x4 __attribute__((ext_vector_type(4)));
typedef short s16x8 __attribute__((ext_vector_type(8)));
typedef float fv2 __attribute__((ext_vector_type(2)));
typedef unsigned short uv4 __attribute__((ext_vector_type(4)));

__device__ __forceinline__ ushort f2bf(float x) {
    unsigned b = __float_as_uint(x);
    return (ushort)((b + 0x7fffu + ((b >> 16) & 1u)) >> 16);  // RNE
}

// ---------------- OCP e4m3 encode/decode (HW cvt if available) --------------

#if defined(__has_builtin)
#if __has_builtin(__builtin_amdgcn_cvt_pk_fp8_f32) && __has_builtin(__builtin_amdgcn_cvt_pk_f32_fp8)
#define FP8_HW 1
#endif
#endif

__device__ __forceinline__ unsigned enc_fp8_scalar(float x) {  // manual OCP e4m3fn, FTZ
    unsigned b = __float_as_uint(x);
    const unsigned s = b >> 31;
    float ax = fabsf(x);
    ax = fminf(ax, 448.f);
    if (ax < 0.015625f) return s << 7;
    unsigned ab = __float_as_uint(ax);
    unsigned lsb = (ab >> 20) & 1u;
    unsigned b2 = ab + 0x7FFFFu + lsb;
    unsigned e = ((b2 >> 23) & 0xFFu) - 120u;
    unsigned m = (b2 >> 20) & 7u;
    if (e > 15u) { e = 15u; m = 6u; }
    return (s << 7) | (e << 3) | m;
}

__device__ __forceinline__ unsigned enc_fp8x4(float4 f) {
#ifdef FP8_HW
    int r = 0;
    r = __builtin_amdgcn_cvt_pk_fp8_f32(f.x, f.y, r, false);
    r = __builtin_amdgcn_cvt_pk_fp8_f32(f.z, f.w, r, true);
    return (unsigned)r;
#else
    return enc_fp8_scalar(f.x) | (enc_fp8_scalar(f.y) << 8) |
           (enc_fp8_scalar(f.z) << 16) | (enc_fp8_scalar(f.w) << 24);
#endif
}

__device__ __forceinline__ float dec_fp8_scalar(unsigned u) {
    unsigned e = (u >> 3) & 15u;
    unsigned bits = ((u & 0x80u) << 24) | (((u & 0x7Fu) << 20) + (120u << 23));
    return (e == 0) ? 0.f : __uint_as_float(bits);
}

__device__ __forceinline__ void dec_fp8x4(unsigned u, float* f) {
#ifdef FP8_HW
    fv2 lo = __builtin_amdgcn_cvt_pk_f32_fp8(u, false);
    fv2 hi = __builtin_amdgcn_cvt_pk_f32_fp8(u, true);
    f[0] = lo.x; f[1] = lo.y; f[2] = hi.x; f[3] = hi.y;
#else
    f[0] = dec_fp8_scalar(u);
    f[1] = dec_fp8_scalar(u >> 8);
    f[2] = dec_fp8_scalar(u >> 16);
    f[3] = dec_fp8_scalar(u >> 24);
#endif
}

// ---------------- fused pre-pass: radix scatter ∥ hb ∥ hsb ∥ Wb -------------
// blocks [0,256): LDS-staged scatter to padded coarse-bucket windows.
// [256,6506): h_neigh->fp8 (hb). [6506,12756): h_self->bf16 (hsb).
// [12756,12792): W->bf16 fragment layout Wb[t][koff8][c][8].
// pk1 entry: x = edge id; y = src(16b) | dl(8b)<<16 | cb(8b)<<24.

__global__ __launch_bounds__(256) void k_pre(const int* __restrict__ dst,
                                             const int* __restrict__ src,
                                             int* __restrict__ gcur0,
                                             int2* __restrict__ pk1,
                                             const float* __restrict__ h_neigh,
                                             unsigned* __restrict__ hb,
                                             const float* __restrict__ h_self,
                                             ushort* __restrict__ hsb,
                                             const float* __restrict__ Wself,
                                             const float* __restrict__ Wneigh,
                                             ushort* __restrict__ Wb) {
    __shared__ int hist[NB];
    __shared__ int lbase[NB];
    __shared__ int gbase[NB];
    __shared__ int partial[256];
    __shared__ int2 stage[CHUNK];
    const int blk = blockIdx.x;
    const int tid = threadIdx.x;

    if (blk >= NSCAT1) {
        const int bb = blk - NSCAT1;
        if (bb < 6250) {                       // hb: f32x4 -> fp8x4
            const int i = bb * 256 + tid;
            float4 f = ((const float4*)h_neigh)[i];
            hb[i] = enc_fp8x4(f);
        } else if (bb < 12500) {               // hsb: f32x4 -> bf16x4
            const int i = (bb - 6250) * 256 + tid;
            float4 f = ((const float4*)h_self)[i];
            ((ushort4*)hsb)[i] = make_ushort4(f2bf(f.x), f2bf(f.y), f2bf(f.z), f2bf(f.w));
        } else {                               // Wb
            const int q = (bb - 12500) * 256 + tid;
            if (q >= 9 * 4 * 256) return;
            const int t = q >> 10;
            const int r = q & 1023;
            const int k8 = r >> 8;
            const int c = r & 255;
            const int kb = t * 32 + k8 * 8;
            const float* p = (kb < 128) ? (Wself + (size_t)c * D_SELF + kb)
                                        : (Wneigh + (size_t)c * D_HN + (kb - 128));
            float4 f0 = *(const float4*)(p);
            float4 f1 = *(const float4*)(p + 4);
            ushort* o = Wb + (size_t)q * 8;
            *(ushort4*)(o)     = make_ushort4(f2bf(f0.x), f2bf(f0.y), f2bf(f0.z), f2bf(f0.w));
            *(ushort4*)(o + 4) = make_ushort4(f2bf(f1.x), f2bf(f1.y), f2bf(f1.z), f2bf(f1.w));
        }
        return;
    }

    // ---- scatter (blocks 0..255) ----
    const int n = N_EDGES;
    for (int c0 = blk * CHUNK; c0 < n; c0 += NSCAT1 * CHUNK) {
        const int m = min(CHUNK, n - c0);
        for (int t = tid; t < NB; t += 256) hist[t] = 0;
        __syncthreads();
        int d8[8], s8[8];
#pragma unroll
        for (int j = 0; j < 8; j++) {
            const int i = c0 + j * 256 + tid;
            if (i < n) { d8[j] = dst[i]; s8[j] = src[i]; atomicAdd(&hist[d8[j] >> 8], 1); }
        }
        __syncthreads();
        // parallel exclusive scan over NB bins (NB <= 256: one bin per thread)
        const int v = (tid < NB) ? hist[tid] : 0;
        partial[tid] = v;
        __syncthreads();
        for (int off = 1; off < 256; off <<= 1) {
            int q = (tid >= off) ? partial[tid - off] : 0;
            __syncthreads();
            partial[tid] += q;
            __syncthreads();
        }
        if (tid < NB) lbase[tid] = partial[tid] - v;
        __syncthreads();
        for (int t = tid; t < NB; t += 256)
            gbase[t] = hist[t] ? atomicAdd(&gcur0[t * CPAD], hist[t]) : 0;
        __syncthreads();
        for (int t = tid; t < NB; t += 256) hist[t] = lbase[t];
        __syncthreads();
#pragma unroll
        for (int j = 0; j < 8; j++) {
            const int i = c0 + j * 256 + tid;
            if (i < n) {
                const unsigned cb = (unsigned)d8[j] >> 8;
                const int p = atomicAdd(&hist[cb], 1);
                stage[p] = make_int2(i, (int)((unsigned)s8[j] |
                                              (((unsigned)d8[j] & 255u) << 16) | (cb << 24)));
            }
        }
        __syncthreads();
        for (int t = tid; t < m; t += 256) {
            int2 v2 = stage[t];
            const int cb = (v2.y >> 24) & 255;
            v2.y &= 0x00FFFFFF;
            pk1[((size_t)cb << CAPSH) + gbase[cb] + (t - lbase[cb])] = v2;
        }
        __syncthreads();
    }
}

// ---------------- pass B: per-bucket sort -> per-dst runs + rs2(start,end) ---

__global__ __launch_bounds__(1024) void k_scat2(const int* __restrict__ gcur0,
                                                const int2* __restrict__ pk1,
                                                int2* __restrict__ pk2,
                                                int2* __restrict__ rs2) {
    __shared__ int part[256];
    __shared__ int cur[256];
    const int b = blockIdx.x;
    const int n = gcur0[b * CPAD];
    const int base = b << CAPSH;
    const int tid = threadIdx.x;
    if (tid < 256) part[tid] = 0;
    __syncthreads();
    for (int i = tid; i < n; i += 1024)
        atomicAdd(&part[(pk1[base + i].y >> 16) & 255], 1);
    __syncthreads();
    const int c0 = (tid < 256) ? part[tid] : 0;
    __syncthreads();
    for (int off = 1; off < 256; off <<= 1) {
        int v = 0;
        if (tid < 256 && tid >= off) v = part[tid - off];
        __syncthreads();
        if (tid < 256) part[tid] += v;
        __syncthreads();
    }
    if (tid < 256) {
        const int pfx = part[tid] - c0;   // exclusive
        cur[tid] = pfx;
        const int gn = b * 256 + tid;
        if (gn < N_DST) rs2[gn] = make_int2(base + pfx, base + pfx + c0);
    }
    __syncthreads();
    for (int i = tid; i < n; i += 1024) {
        int2 v = pk1[base + i];
        const int dl = (v.y >> 16) & 255;
        const int p = atomicAdd(&cur[dl], 1);
        pk2[base + p] = make_int2(v.x, v.y & 0xFFFF);
    }
}

// ---------------- Aggregation: one wave per dst, 2 dsts per block -----------
// Half-wave split gathers; hb rows fp8 e4m3 (128B/row, 4B/lane).
// Zero-reuse streams (pk, ef) NON-TEMPORAL; hb stays cache-resident.
// 128-thread blocks (2 independent waves): full wave occupancy with half
// the workgroup slots (R2-R7 showed 83% occ with 1-wave workgroups).

__global__ __launch_bounds__(128) void k_agg(const int2* __restrict__ rs2,
                                             const int2* __restrict__ pk,
                                             const unsigned char* __restrict__ hb,
                                             const float* __restrict__ ef,
                                             ushort* __restrict__ hnb) {
    const int d = blockIdx.x * 2 + (threadIdx.x >> 6);
    const int lane = threadIdx.x & 63;
    if (d >= N_DST) return;
    const int ll = lane & 31;
    const int g = lane >> 5;
    const int2 se = rs2[d];
    const int start = se.x, end = se.y;
    const int deg = end - start;
    float a0 = 0.f, a1 = 0.f, a2 = 0.f, a3 = 0.f, ae = 0.f;
    const unsigned char* hbase = hb + 4 * ll;
    const float* ebase = ef + ll;

    for (int c = start; c < end; c += 64) {
        const int rem = end - c;
        const int m = rem < 64 ? rem : 64;
        int e = 0, s = 0;
        if (lane < m) {
            unsigned long long pv =
                __builtin_nontemporal_load((const unsigned long long*)&pk[c + lane]);
            e = (int)(unsigned)pv;
            s = (int)(unsigned)(pv >> 32);
        }
        int i = 0;
        for (; i + 16 <= m; i += 16) {
            unsigned u[8];
            float te[8];
#pragma unroll
            for (int j = 0; j < 8; j++) {
                const int sj = __shfl(s, i + 2 * j + g);
                u[j] = *(const unsigned*)(hbase + (size_t)sj * D_NEIGH);
            }
#pragma unroll
            for (int j = 0; j < 8; j++) {
                const int ee = __shfl(e, i + 2 * j + g);
                te[j] = __builtin_nontemporal_load(ebase + (size_t)ee * D_EDGE);
            }
#pragma unroll
            for (int j = 0; j < 8; j++) {
                float f[4];
                dec_fp8x4(u[j], f);
                a0 += f[0]; a1 += f[1]; a2 += f[2]; a3 += f[3];
                ae += te[j];
            }
        }
        for (; i + 8 <= m; i += 8) {
            unsigned u[4];
            float te[4];
#pragma unroll
            for (int j = 0; j < 4; j++) {
                const int sj = __shfl(s, i + 2 * j + g);
                u[j] = *(const unsigned*)(hbase + (size_t)sj * D_NEIGH);
            }
#pragma unroll
            for (int j = 0; j < 4; j++) {
                const int ee = __shfl(e, i + 2 * j + g);
                te[j] = __builtin_nontemporal_load(ebase + (size_t)ee * D_EDGE);
            }
#pragma unroll
            for (int j = 0; j < 4; j++) {
                float f[4];
                dec_fp8x4(u[j], f);
                a0 += f[0]; a1 += f[1]; a2 += f[2]; a3 += f[3];
                ae += te[j];
            }
        }
        for (; i < m; ++i) {   // tail singles: half-wave 0 only
            const int si = __builtin_amdgcn_readlane(s, i);
            const int ei = __builtin_amdgcn_readlane(e, i);
            if (g == 0) {
                const unsigned uu = *(const unsigned*)(hbase + (size_t)si * D_NEIGH);
                float f[4];
                dec_fp8x4(uu, f);
                a0 += f[0]; a1 += f[1]; a2 += f[2]; a3 += f[3];
                ae += __builtin_nontemporal_load(ebase + (size_t)ei * D_EDGE);
            }
        }
    }

    a0 += __shfl_xor(a0, 32); a1 += __shfl_xor(a1, 32);
    a2 += __shfl_xor(a2, 32); a3 += __shfl_xor(a3, 32);
    ae += __shfl_xor(ae, 32);

    if (lane < 32) {
        const float inv = 1.0f / (float)(deg > 0 ? deg : 1);
        ushort* o = hnb + (size_t)d * D_HN;
        *(ushort4*)(o + 4 * ll) = make_ushort4(f2bf(a0 * inv), f2bf(a1 * inv),
                                               f2bf(a2 * inv), f2bf(a3 * inv));
        o[128 + ll] = f2bf(ae * inv);
    }
}

// ---------------- Fused bf16-MFMA GEMM + ReLU + row-L2-norm ----------------
// 128x256, 512 threads (8 waves 4x2). X (hsb|hnb bf16): LDS double-buffered,
// one barrier per K-step. W: B-fragments from L2-resident Wb.

#define GBM 128

__global__ __launch_bounds__(512) void k_gemm_norm(const ushort* __restrict__ hsb,
                                                   const ushort* __restrict__ hnb,
                                                   const ushort* __restrict__ Wb,
                                                   float* __restrict__ out) {
    __shared__ __align__(16) ushort Xs[2][GBM * 40];
    __shared__ float rsum[2][GBM];
    __shared__ float invn[GBM];

    const int tid = threadIdx.x;
    const int lane = tid & 63;
    const int wid = tid >> 6;
    const int wm = wid >> 1;
    const int wn = wid & 1;
    const int brow = blockIdx.x * GBM;
    const int xrow = tid >> 2, xpart = tid & 3;
    const int koff8 = lane >> 4, rsel = lane & 15;

    f32x4 acc[2][8] = {};

    auto stageX = [&](int t, int bufi) {
        const int k0 = t * 32;
        const int gr = brow + xrow;
        uv4 v0 = (uv4)0, v1 = (uv4)0;
        if (gr < N_DST) {
            const ushort* sp = (k0 < 128) ? (hsb + (size_t)gr * D_SELF + k0 + xpart * 8)
                                          : (hnb + (size_t)gr * D_HN + (k0 - 128) + xpart * 8);
            v0 = __builtin_nontemporal_load((const uv4*)(sp));
            v1 = __builtin_nontemporal_load((const uv4*)(sp + 4));
        }
        *(uv4*)&Xs[bufi][xrow * 40 + xpart * 8] = v0;
        *(uv4*)&Xs[bufi][xrow * 40 + xpart * 8 + 4] = v1;
    };

    stageX(0, 0);
    __syncthreads();

    for (int t = 0; t < 9; t++) {
        if (t < 8) stageX(t + 1, (t + 1) & 1);
        s16x8 af[2], bf[8];
#pragma unroll
        for (int fi = 0; fi < 2; fi++)
            af[fi] = *(const s16x8*)&Xs[t & 1][(wm * 32 + fi * 16 + rsel) * 40 + koff8 * 8];
#pragma unroll
        for (int fj = 0; fj < 8; fj++)
            bf[fj] = *(const s16x8*)&Wb[((size_t)(t * 4 + koff8) * 256 +
                                         (wn * 128 + fj * 16 + rsel)) * 8];
#pragma unroll
        for (int fi = 0; fi < 2; fi++)
#pragma unroll
            for (int fj = 0; fj < 8; fj++)
                acc[fi][fj] = __builtin_amdgcn_mfma_f32_16x16x32_bf16(af[fi], bf[fj], acc[fi][fj], 0, 0, 0);
        __syncthreads();
    }

    float ss[2][4];
#pragma unroll
    for (int fi = 0; fi < 2; fi++)
#pragma unroll
        for (int j = 0; j < 4; j++) {
            float s = 0.f;
#pragma unroll
            for (int fj = 0; fj < 8; fj++) {
                float z = fmaxf(acc[fi][fj][j], 0.f);
                acc[fi][fj][j] = z;
                s += z * z;
            }
            ss[fi][j] = s;
        }
#pragma unroll
    for (int m = 1; m < 16; m <<= 1)
#pragma unroll
        for (int fi = 0; fi < 2; fi++)
#pragma unroll
            for (int j = 0; j < 4; j++) ss[fi][j] += __shfl_xor(ss[fi][j], m);
    if ((lane & 15) == 0) {
        const int gg = lane >> 4;
#pragma unroll
        for (int fi = 0; fi < 2; fi++)
#pragma unroll
            for (int j = 0; j < 4; j++)
                rsum[wn][wm * 32 + fi * 16 + gg * 4 + j] = ss[fi][j];
    }
    __syncthreads();
    if (tid < GBM) {
        float t = rsum[0][tid] + rsum[1][tid];
        invn[tid] = (t > 0.f) ? 1.f / sqrtf(t) : 1.f;
    }
    __syncthreads();

#pragma unroll
    for (int fi = 0; fi < 2; fi++)
#pragma unroll
        for (int j = 0; j < 4; j++) {
            const int rl = wm * 32 + fi * 16 + (lane >> 4) * 4 + j;
            const int row = brow + rl;
            if (row < N_DST) {
                const float iv = invn[rl];
#pragma unroll
                for (int fj = 0; fj < 8; fj++)
                    __builtin_nontemporal_store(acc[fi][fj][j] * iv,
                        &out[(size_t)row * D_OUT + wn * 128 + fj * 16 + (lane & 15)]);
            }
        }
}

// ---------------- launch ----------------

extern "C" void kernel_launch(void* const* d_in, const int* in_sizes, int n_in,
                              void* d_out, int out_size, void* d_ws, size_t ws_size,
                              hipStream_t stream) {
    const float* h_neigh = (const float*)d_in[0];
    const float* h_self  = (const float*)d_in[1];
    const float* ef      = (const float*)d_in[2];
    const int*   src     = (const int*)d_in[3];
    const int*   dst     = (const int*)d_in[4];
    const float* Wself   = (const float*)d_in[5];
    const float* Wneigh  = (const float*)d_in[6];
    float* out = (float*)d_out;

    char* ws = (char*)d_ws;
    int*      gcur0 = (int*)(ws + 0);                          // 12.5KB, reserve 16KB
    int2*     rs2   = (int2*)(ws + 16384);                     // 400KB, reserve to 512KB
    int2*     pk1   = (int2*)(ws + 524288);                    // 25.7MB -> 26,214,400
    int2*     pk2   = (int2*)(ws + 26214400);                  // 25.7MB -> 51,904,512
    unsigned* hb    = (unsigned*)(ws + 51904512);              // 6.4MB  -> 58,304,512
    ushort*   hsb   = (ushort*)(ws + 58304512);                // 12.8MB -> 71,104,512
    ushort*   hnb   = (ushort*)(ws + 71104512);                // 16MB   -> 87,104,512
    ushort*   Wb    = (ushort*)(ws + 87104512);                // 147KB  -> 87,251,968

    hipMemsetAsync(gcur0, 0, NB * CPAD * sizeof(int), stream);
    k_pre<<<NSCAT1 + 6250 + 6250 + 36, 256, 0, stream>>>(dst, src, gcur0, pk1,
                                                         h_neigh, hb, h_self, hsb,
                                                         Wself, Wneigh, Wb);
    k_scat2<<<NB, 1024, 0, stream>>>(gcur0, pk1, pk2, rs2);
    k_agg<<<(N_DST + 1) / 2, 128, 0, stream>>>(rs2, pk2, (const unsigned char*)hb, ef, hnb);
    k_gemm_norm<<<(N_DST + GBM - 1) / GBM, 512, 0, stream>>>(hsb, hnb, Wb, out);
}

// Round 18
// 148.296 us; speedup vs baseline: 1.1286x; 1.0260x over previous
//
#include <hip/hip_runtime.h>

#define N_SRC 50000
#define N_DST 50000
#define N_EDGES 1600000
#define D_NEIGH 128
#define D_SELF 128
#define D_EDGE 32
#define D_OUT 256
#define K_TOT 288
#define D_HN 160

#define NB 196      // coarse buckets of 256 dst nodes (CHUNK/NB ~10 entries: full-line bursts)
#define CPAD 16     // one counter per 64B line
#define CHUNK 2048
#define CAPSH 14    // 16384-entry padded window per bucket (mean 8163, +90 sigma)
#define NSCAT1 256  // scatter blocks inside k_pre

typedef float f32x4 __attribute__((ext_vector_type(4)));
typedef short s16x8 __attribute__((ext_vector_type(8)));
typedef float fv2 __attribute__((ext_vector_type(2)));
typedef unsigned short uv4 __attribute__((ext_vector_type(4)));

__device__ __forceinline__ ushort f2bf(float x) {
    unsigned b = __float_as_uint(x);
    return (ushort)((b + 0x7fffu + ((b >> 16) & 1u)) >> 16);  // RNE
}

// ---------------- OCP e4m3 encode/decode (HW cvt if available) --------------

#if defined(__has_builtin)
#if __has_builtin(__builtin_amdgcn_cvt_pk_fp8_f32) && __has_builtin(__builtin_amdgcn_cvt_pk_f32_fp8)
#define FP8_HW 1
#endif
#endif

__device__ __forceinline__ unsigned enc_fp8_scalar(float x) {  // manual OCP e4m3fn, FTZ
    unsigned b = __float_as_uint(x);
    const unsigned s = b >> 31;
    float ax = fabsf(x);
    ax = fminf(ax, 448.f);
    if (ax < 0.015625f) return s << 7;
    unsigned ab = __float_as_uint(ax);
    unsigned lsb = (ab >> 20) & 1u;
    unsigned b2 = ab + 0x7FFFFu + lsb;
    unsigned e = ((b2 >> 23) & 0xFFu) - 120u;
    unsigned m = (b2 >> 20) & 7u;
    if (e > 15u) { e = 15u; m = 6u; }
    return (s << 7) | (e << 3) | m;
}

__device__ __forceinline__ unsigned enc_fp8x4(float4 f) {
#ifdef FP8_HW
    int r = 0;
    r = __builtin_amdgcn_cvt_pk_fp8_f32(f.x, f.y, r, false);
    r = __builtin_amdgcn_cvt_pk_fp8_f32(f.z, f.w, r, true);
    return (unsigned)r;
#else
    return enc_fp8_scalar(f.x) | (enc_fp8_scalar(f.y) << 8) |
           (enc_fp8_scalar(f.z) << 16) | (enc_fp8_scalar(f.w) << 24);
#endif
}

__device__ __forceinline__ float dec_fp8_scalar(unsigned u) {
    unsigned e = (u >> 3) & 15u;
    unsigned bits = ((u & 0x80u) << 24) | (((u & 0x7Fu) << 20) + (120u << 23));
    return (e == 0) ? 0.f : __uint_as_float(bits);
}

__device__ __forceinline__ void dec_fp8x4(unsigned u, float* f) {
#ifdef FP8_HW
    fv2 lo = __builtin_amdgcn_cvt_pk_f32_fp8(u, false);
    fv2 hi = __builtin_amdgcn_cvt_pk_f32_fp8(u, true);
    f[0] = lo.x; f[1] = lo.y; f[2] = hi.x; f[3] = hi.y;
#else
    f[0] = dec_fp8_scalar(u);
    f[1] = dec_fp8_scalar(u >> 8);
    f[2] = dec_fp8_scalar(u >> 16);
    f[3] = dec_fp8_scalar(u >> 24);
#endif
}

// ---------------- fused pre-pass: radix scatter ∥ hb ∥ hsb ∥ Wb -------------
// blocks [0,256): LDS-staged scatter to padded coarse-bucket windows.
// [256,6506): h_neigh->fp8 (hb). [6506,12756): h_self->bf16 (hsb).
// [12756,12792): W->bf16 fragment layout Wb[t][koff8][c][8].
// pk1 entry: x = edge id; y = src(16b) | dl(8b)<<16 | cb(8b)<<24.

__global__ __launch_bounds__(256) void k_pre(const int* __restrict__ dst,
                                             const int* __restrict__ src,
                                             int* __restrict__ gcur0,
                                             int2* __restrict__ pk1,
                                             const float* __restrict__ h_neigh,
                                             unsigned* __restrict__ hb,
                                             const float* __restrict__ h_self,
                                             ushort* __restrict__ hsb,
                                             const float* __restrict__ Wself,
                                             const float* __restrict__ Wneigh,
                                             ushort* __restrict__ Wb) {
    __shared__ int hist[NB];
    __shared__ int lbase[NB];
    __shared__ int gbase[NB];
    __shared__ int partial[256];
    __shared__ int2 stage[CHUNK];
    const int blk = blockIdx.x;
    const int tid = threadIdx.x;

    if (blk >= NSCAT1) {
        const int bb = blk - NSCAT1;
        if (bb < 6250) {                       // hb: f32x4 -> fp8x4
            const int i = bb * 256 + tid;
            float4 f = ((const float4*)h_neigh)[i];
            hb[i] = enc_fp8x4(f);
        } else if (bb < 12500) {               // hsb: f32x4 -> bf16x4
            const int i = (bb - 6250) * 256 + tid;
            float4 f = ((const float4*)h_self)[i];
            ((ushort4*)hsb)[i] = make_ushort4(f2bf(f.x), f2bf(f.y), f2bf(f.z), f2bf(f.w));
        } else {                               // Wb
            const int q = (bb - 12500) * 256 + tid;
            if (q >= 9 * 4 * 256) return;
            const int t = q >> 10;
            const int r = q & 1023;
            const int k8 = r >> 8;
            const int c = r & 255;
            const int kb = t * 32 + k8 * 8;
            const float* p = (kb < 128) ? (Wself + (size_t)c * D_SELF + kb)
                                        : (Wneigh + (size_t)c * D_HN + (kb - 128));
            float4 f0 = *(const float4*)(p);
            float4 f1 = *(const float4*)(p + 4);
            ushort* o = Wb + (size_t)q * 8;
            *(ushort4*)(o)     = make_ushort4(f2bf(f0.x), f2bf(f0.y), f2bf(f0.z), f2bf(f0.w));
            *(ushort4*)(o + 4) = make_ushort4(f2bf(f1.x), f2bf(f1.y), f2bf(f1.z), f2bf(f1.w));
        }
        return;
    }

    // ---- scatter (blocks 0..255) ----
    const int n = N_EDGES;
    for (int c0 = blk * CHUNK; c0 < n; c0 += NSCAT1 * CHUNK) {
        const int m = min(CHUNK, n - c0);
        for (int t = tid; t < NB; t += 256) hist[t] = 0;
        __syncthreads();
        int d8[8], s8[8];
#pragma unroll
        for (int j = 0; j < 8; j++) {
            const int i = c0 + j * 256 + tid;
            if (i < n) { d8[j] = dst[i]; s8[j] = src[i]; atomicAdd(&hist[d8[j] >> 8], 1); }
        }
        __syncthreads();
        // parallel exclusive scan over NB bins (NB <= 256: one bin per thread)
        const int v = (tid < NB) ? hist[tid] : 0;
        partial[tid] = v;
        __syncthreads();
        for (int off = 1; off < 256; off <<= 1) {
            int q = (tid >= off) ? partial[tid - off] : 0;
            __syncthreads();
            partial[tid] += q;
            __syncthreads();
        }
        if (tid < NB) lbase[tid] = partial[tid] - v;
        __syncthreads();
        for (int t = tid; t < NB; t += 256)
            gbase[t] = hist[t] ? atomicAdd(&gcur0[t * CPAD], hist[t]) : 0;
        __syncthreads();
        for (int t = tid; t < NB; t += 256) hist[t] = lbase[t];
        __syncthreads();
#pragma unroll
        for (int j = 0; j < 8; j++) {
            const int i = c0 + j * 256 + tid;
            if (i < n) {
                const unsigned cb = (unsigned)d8[j] >> 8;
                const int p = atomicAdd(&hist[cb], 1);
                stage[p] = make_int2(i, (int)((unsigned)s8[j] |
                                              (((unsigned)d8[j] & 255u) << 16) | (cb << 24)));
            }
        }
        __syncthreads();
        for (int t = tid; t < m; t += 256) {
            int2 v2 = stage[t];
            const int cb = (v2.y >> 24) & 255;
            v2.y &= 0x00FFFFFF;
            pk1[((size_t)cb << CAPSH) + gbase[cb] + (t - lbase[cb])] = v2;
        }
        __syncthreads();
    }
}

// ---------------- pass B: per-bucket sort -> per-dst runs + rs2(start,end) ---

__global__ __launch_bounds__(1024) void k_scat2(const int* __restrict__ gcur0,
                                                const int2* __restrict__ pk1,
                                                int2* __restrict__ pk2,
                                                int2* __restrict__ rs2) {
    __shared__ int part[256];
    __shared__ int cur[256];
    const int b = blockIdx.x;
    const int n = gcur0[b * CPAD];
    const int base = b << CAPSH;
    const int tid = threadIdx.x;
    if (tid < 256) part[tid] = 0;
    __syncthreads();
    for (int i = tid; i < n; i += 1024)
        atomicAdd(&part[(pk1[base + i].y >> 16) & 255], 1);
    __syncthreads();
    const int c0 = (tid < 256) ? part[tid] : 0;
    __syncthreads();
    for (int off = 1; off < 256; off <<= 1) {
        int v = 0;
        if (tid < 256 && tid >= off) v = part[tid - off];
        __syncthreads();
        if (tid < 256) part[tid] += v;
        __syncthreads();
    }
    if (tid < 256) {
        const int pfx = part[tid] - c0;   // exclusive
        cur[tid] = pfx;
        const int gn = b * 256 + tid;
        if (gn < N_DST) rs2[gn] = make_int2(base + pfx, base + pfx + c0);
    }
    __syncthreads();
    for (int i = tid; i < n; i += 1024) {
        int2 v = pk1[base + i];
        const int dl = (v.y >> 16) & 255;
        const int p = atomicAdd(&cur[dl], 1);
        pk2[base + p] = make_int2(v.x, v.y & 0xFFFF);
    }
}

// ---------------- Aggregation: one wave per dst node ----------------
// Half-wave split gathers; hb rows fp8 e4m3 (128B/row, 4B/lane).
// Zero-reuse streams (pk, ef) NON-TEMPORAL; hb stays cache-resident.
// 1-wave blocks, 50K-wide grid: best measured shape (R15; R14/R16/R17
// alternatives all regressed or were null).

__global__ __launch_bounds__(64) void k_agg(const int2* __restrict__ rs2,
                                            const int2* __restrict__ pk,
                                            const unsigned char* __restrict__ hb,
                                            const float* __restrict__ ef,
                                            ushort* __restrict__ hnb) {
    const int d = blockIdx.x;
    const int lane = threadIdx.x;
    const int ll = lane & 31;
    const int g = lane >> 5;
    const int2 se = rs2[d];
    const int start = se.x, end = se.y;
    const int deg = end - start;
    float a0 = 0.f, a1 = 0.f, a2 = 0.f, a3 = 0.f, ae = 0.f;
    const unsigned char* hbase = hb + 4 * ll;
    const float* ebase = ef + ll;

    for (int c = start; c < end; c += 64) {
        const int rem = end - c;
        const int m = rem < 64 ? rem : 64;
        int e = 0, s = 0;
        if (lane < m) {
            unsigned long long pv =
                __builtin_nontemporal_load((const unsigned long long*)&pk[c + lane]);
            e = (int)(unsigned)pv;
            s = (int)(unsigned)(pv >> 32);
        }
        int i = 0;
        for (; i + 16 <= m; i += 16) {
            unsigned u[8];
            float te[8];
#pragma unroll
            for (int j = 0; j < 8; j++) {
                const int sj = __shfl(s, i + 2 * j + g);
                u[j] = *(const unsigned*)(hbase + (size_t)sj * D_NEIGH);
            }
#pragma unroll
            for (int j = 0; j < 8; j++) {
                const int ee = __shfl(e, i + 2 * j + g);
                te[j] = __builtin_nontemporal_load(ebase + (size_t)ee * D_EDGE);
            }
#pragma unroll
            for (int j = 0; j < 8; j++) {
                float f[4];
                dec_fp8x4(u[j], f);
                a0 += f[0]; a1 += f[1]; a2 += f[2]; a3 += f[3];
                ae += te[j];
            }
        }
        for (; i + 8 <= m; i += 8) {
            unsigned u[4];
            float te[4];
#pragma unroll
            for (int j = 0; j < 4; j++) {
                const int sj = __shfl(s, i + 2 * j + g);
                u[j] = *(const unsigned*)(hbase + (size_t)sj * D_NEIGH);
            }
#pragma unroll
            for (int j = 0; j < 4; j++) {
                const int ee = __shfl(e, i + 2 * j + g);
                te[j] = __builtin_nontemporal_load(ebase + (size_t)ee * D_EDGE);
            }
#pragma unroll
            for (int j = 0; j < 4; j++) {
                float f[4];
                dec_fp8x4(u[j], f);
                a0 += f[0]; a1 += f[1]; a2 += f[2]; a3 += f[3];
                ae += te[j];
            }
        }
        for (; i < m; ++i) {   // tail singles: half-wave 0 only
            const int si = __builtin_amdgcn_readlane(s, i);
            const int ei = __builtin_amdgcn_readlane(e, i);
            if (g == 0) {
                const unsigned uu = *(const unsigned*)(hbase + (size_t)si * D_NEIGH);
                float f[4];
                dec_fp8x4(uu, f);
                a0 += f[0]; a1 += f[1]; a2 += f[2]; a3 += f[3];
                ae += __builtin_nontemporal_load(ebase + (size_t)ei * D_EDGE);
            }
        }
    }

    a0 += __shfl_xor(a0, 32); a1 += __shfl_xor(a1, 32);
    a2 += __shfl_xor(a2, 32); a3 += __shfl_xor(a3, 32);
    ae += __shfl_xor(ae, 32);

    if (lane < 32) {
        const float inv = 1.0f / (float)(deg > 0 ? deg : 1);
        ushort* o = hnb + (size_t)d * D_HN;
        *(ushort4*)(o + 4 * ll) = make_ushort4(f2bf(a0 * inv), f2bf(a1 * inv),
                                               f2bf(a2 * inv), f2bf(a3 * inv));
        o[128 + ll] = f2bf(ae * inv);
    }
}

// ---------------- Fused bf16-MFMA GEMM + ReLU + row-L2-norm ----------------
// 128x256, 512 threads (8 waves 4x2). X (hsb|hnb bf16): LDS double-buffered,
// one barrier per K-step. W: B-fragments from L2-resident Wb.

#define GBM 128

__global__ __launch_bounds__(512) void k_gemm_norm(const ushort* __restrict__ hsb,
                                                   const ushort* __restrict__ hnb,
                                                   const ushort* __restrict__ Wb,
                                                   float* __restrict__ out) {
    __shared__ __align__(16) ushort Xs[2][GBM * 40];
    __shared__ float rsum[2][GBM];
    __shared__ float invn[GBM];

    const int tid = threadIdx.x;
    const int lane = tid & 63;
    const int wid = tid >> 6;
    const int wm = wid >> 1;
    const int wn = wid & 1;
    const int brow = blockIdx.x * GBM;
    const int xrow = tid >> 2, xpart = tid & 3;
    const int koff8 = lane >> 4, rsel = lane & 15;

    f32x4 acc[2][8] = {};

    auto stageX = [&](int t, int bufi) {
        const int k0 = t * 32;
        const int gr = brow + xrow;
        uv4 v0 = (uv4)0, v1 = (uv4)0;
        if (gr < N_DST) {
            const ushort* sp = (k0 < 128) ? (hsb + (size_t)gr * D_SELF + k0 + xpart * 8)
                                          : (hnb + (size_t)gr * D_HN + (k0 - 128) + xpart * 8);
            v0 = __builtin_nontemporal_load((const uv4*)(sp));
            v1 = __builtin_nontemporal_load((const uv4*)(sp + 4));
        }
        *(uv4*)&Xs[bufi][xrow * 40 + xpart * 8] = v0;
        *(uv4*)&Xs[bufi][xrow * 40 + xpart * 8 + 4] = v1;
    };

    stageX(0, 0);
    __syncthreads();

    for (int t = 0; t < 9; t++) {
        if (t < 8) stageX(t + 1, (t + 1) & 1);
        s16x8 af[2], bf[8];
#pragma unroll
        for (int fi = 0; fi < 2; fi++)
            af[fi] = *(const s16x8*)&Xs[t & 1][(wm * 32 + fi * 16 + rsel) * 40 + koff8 * 8];
#pragma unroll
        for (int fj = 0; fj < 8; fj++)
            bf[fj] = *(const s16x8*)&Wb[((size_t)(t * 4 + koff8) * 256 +
                                         (wn * 128 + fj * 16 + rsel)) * 8];
#pragma unroll
        for (int fi = 0; fi < 2; fi++)
#pragma unroll
            for (int fj = 0; fj < 8; fj++)
                acc[fi][fj] = __builtin_amdgcn_mfma_f32_16x16x32_bf16(af[fi], bf[fj], acc[fi][fj], 0, 0, 0);
        __syncthreads();
    }

    float ss[2][4];
#pragma unroll
    for (int fi = 0; fi < 2; fi++)
#pragma unroll
        for (int j = 0; j < 4; j++) {
            float s = 0.f;
#pragma unroll
            for (int fj = 0; fj < 8; fj++) {
                float z = fmaxf(acc[fi][fj][j], 0.f);
                acc[fi][fj][j] = z;
                s += z * z;
            }
            ss[fi][j] = s;
        }
#pragma unroll
    for (int m = 1; m < 16; m <<= 1)
#pragma unroll
        for (int fi = 0; fi < 2; fi++)
#pragma unroll
            for (int j = 0; j < 4; j++) ss[fi][j] += __shfl_xor(ss[fi][j], m);
    if ((lane & 15) == 0) {
        const int gg = lane >> 4;
#pragma unroll
        for (int fi = 0; fi < 2; fi++)
#pragma unroll
            for (int j = 0; j < 4; j++)
                rsum[wn][wm * 32 + fi * 16 + gg * 4 + j] = ss[fi][j];
    }
    __syncthreads();
    if (tid < GBM) {
        float t = rsum[0][tid] + rsum[1][tid];
        invn[tid] = (t > 0.f) ? 1.f / sqrtf(t) : 1.f;
    }
    __syncthreads();

#pragma unroll
    for (int fi = 0; fi < 2; fi++)
#pragma unroll
        for (int j = 0; j < 4; j++) {
            const int rl = wm * 32 + fi * 16 + (lane >> 4) * 4 + j;
            const int row = brow + rl;
            if (row < N_DST) {
                const float iv = invn[rl];
#pragma unroll
                for (int fj = 0; fj < 8; fj++)
                    __builtin_nontemporal_store(acc[fi][fj][j] * iv,
                        &out[(size_t)row * D_OUT + wn * 128 + fj * 16 + (lane & 15)]);
            }
        }
}

// ---------------- launch ----------------

extern "C" void kernel_launch(void* const* d_in, const int* in_sizes, int n_in,
                              void* d_out, int out_size, void* d_ws, size_t ws_size,
                              hipStream_t stream) {
    const float* h_neigh = (const float*)d_in[0];
    const float* h_self  = (const float*)d_in[1];
    const float* ef      = (const float*)d_in[2];
    const int*   src     = (const int*)d_in[3];
    const int*   dst     = (const int*)d_in[4];
    const float* Wself   = (const float*)d_in[5];
    const float* Wneigh  = (const float*)d_in[6];
    float* out = (float*)d_out;

    char* ws = (char*)d_ws;
    int*      gcur0 = (int*)(ws + 0);                          // 12.5KB, reserve 16KB
    int2*     rs2   = (int2*)(ws + 16384);                     // 400KB, reserve to 512KB
    int2*     pk1   = (int2*)(ws + 524288);                    // 25.7MB -> 26,214,400
    int2*     pk2   = (int2*)(ws + 26214400);                  // 25.7MB -> 51,904,512
    unsigned* hb    = (unsigned*)(ws + 51904512);              // 6.4MB  -> 58,304,512
    ushort*   hsb   = (ushort*)(ws + 58304512);                // 12.8MB -> 71,104,512
    ushort*   hnb   = (ushort*)(ws + 71104512);                // 16MB   -> 87,104,512
    ushort*   Wb    = (ushort*)(ws + 87104512);                // 147KB  -> 87,251,968

    hipMemsetAsync(gcur0, 0, NB * CPAD * sizeof(int), stream);
    k_pre<<<NSCAT1 + 6250 + 6250 + 36, 256, 0, stream>>>(dst, src, gcur0, pk1,
                                                         h_neigh, hb, h_self, hsb,
                                                         Wself, Wneigh, Wb);
    k_scat2<<<NB, 1024, 0, stream>>>(gcur0, pk1, pk2, rs2);
    k_agg<<<N_DST, 64, 0, stream>>>(rs2, pk2, (const unsigned char*)hb, ef, hnb);
    k_gemm_norm<<<(N_DST + GBM - 1) / GBM, 512, 0, stream>>>(hsb, hnb, Wb, out);
}